// Round 1
// baseline (1647.790 us; speedup 1.0000x reference)
//
#include <hip/hip_runtime.h>
#include <hip/hip_bf16.h>
#include <math.h>

#define B_ 4
#define S_ 1024
#define T_ (B_ * S_)      // 4096 tokens
#define D_ 1024
#define H_ 4096
#define E_ 8
#define K_ 2
#define A_ (T_ * K_)      // 8192 assignments

typedef __bf16 bf16x8_t __attribute__((ext_vector_type(8)));
typedef float f32x4_t __attribute__((ext_vector_type(4)));

__device__ inline unsigned short f2bf(float f) {
    __hip_bfloat16 h = __float2bfloat16(f);
    return *reinterpret_cast<unsigned short*>(&h);
}

// ---------------- router: logits -> softmax -> top2 -> weights + stats ----
__global__ void router_kernel(const float* __restrict__ x, const float* __restrict__ rw,
                              int* __restrict__ tok_e, float* __restrict__ tok_w,
                              int* __restrict__ counts, float* __restrict__ probs_sum) {
    int wave = threadIdx.x >> 6;
    int lane = threadIdx.x & 63;
    int token = blockIdx.x * 4 + wave;
    if (token >= T_) return;
    const float* xr = x + (long)token * D_;
    float acc[E_];
#pragma unroll
    for (int e = 0; e < E_; ++e) acc[e] = 0.f;
    for (int i = 0; i < D_ / 64; ++i) {
        int d = i * 64 + lane;
        float xv = xr[d];
        const float* w = rw + (long)d * E_;
#pragma unroll
        for (int e = 0; e < E_; ++e) acc[e] += xv * w[e];
    }
#pragma unroll
    for (int e = 0; e < E_; ++e) {
        for (int off = 32; off > 0; off >>= 1)
            acc[e] += __shfl_down(acc[e], off);
    }
    if (lane == 0) {
        float m = acc[0];
        for (int e = 1; e < E_; ++e) m = fmaxf(m, acc[e]);
        float p[E_], s = 0.f;
        for (int e = 0; e < E_; ++e) { p[e] = expf(acc[e] - m); s += p[e]; }
        float inv = 1.f / s;
        for (int e = 0; e < E_; ++e) p[e] *= inv;
        int i0 = 0;
        for (int e = 1; e < E_; ++e) if (p[e] > p[i0]) i0 = e;
        int i1 = (i0 == 0) ? 1 : 0;
        for (int e = 0; e < E_; ++e) if (e != i0 && p[e] > p[i1]) i1 = e;
        float w0 = p[i0], w1 = p[i1];
        float inv2 = 1.f / (w0 + w1 + 1e-8f);
        w0 *= inv2; w1 *= inv2;
        tok_e[token * 2] = i0;
        tok_e[token * 2 + 1] = i1;
        tok_w[token * 2] = w0;
        tok_w[token * 2 + 1] = w1;
        atomicAdd(&counts[i0], 1);
        atomicAdd(&counts[i1], 1);
        for (int e = 0; e < E_; ++e) atomicAdd(&probs_sum[e], p[e]);
    }
}

// ---------------- offsets (serial, E=8) + aux loss ------------------------
__global__ void offsets_aux_kernel(const int* __restrict__ counts,
                                   const float* __restrict__ probs_sum,
                                   int* __restrict__ offsets, float* __restrict__ aux_out) {
    if (threadIdx.x == 0 && blockIdx.x == 0) {
        int run = 0;
        for (int e = 0; e < E_; ++e) { offsets[e] = run; run += counts[e]; }
        offsets[E_] = run;
        float aux = 0.f;
        for (int e = 0; e < E_; ++e)
            aux += (probs_sum[e] / (float)T_) * ((float)counts[e] / (float)A_);
        *aux_out = (float)E_ * aux;
    }
}

// ---------------- scatter assignments into per-expert groups --------------
__global__ void scatter_kernel(const int* __restrict__ tok_e, const float* __restrict__ tok_w,
                               const int* __restrict__ offsets, int* __restrict__ cursors,
                               int* __restrict__ perm_token, float* __restrict__ perm_weight) {
    int i = blockIdx.x * blockDim.x + threadIdx.x;
    if (i >= A_) return;
    int e = tok_e[i];
    float w = tok_w[i];
    int pos = offsets[e] + atomicAdd(&cursors[e], 1);
    perm_token[pos] = i >> 1;
    perm_weight[pos] = w;
}

// ---------------- fp32 -> bf16 cast of x ----------------------------------
__global__ void cast_x_kernel(const float* __restrict__ x, unsigned short* __restrict__ xb) {
    long i = (long)blockIdx.x * blockDim.x + threadIdx.x;
    float4 v = reinterpret_cast<const float4*>(x)[i];
    unsigned long long packed = (unsigned long long)f2bf(v.x)
        | ((unsigned long long)f2bf(v.y) << 16)
        | ((unsigned long long)f2bf(v.z) << 32)
        | ((unsigned long long)f2bf(v.w) << 48);
    reinterpret_cast<unsigned long long*>(xb)[i] = packed;
}

// ---------------- fp32 [R][C] -> bf16 [C][R] per expert -------------------
__global__ void transpose_cast_kernel(const float* __restrict__ in, unsigned short* __restrict__ out,
                                      int R, int C) {
    __shared__ float tile[32][33];
    long e = blockIdx.z;
    const float* in_e = in + e * (long)R * C;
    unsigned short* out_e = out + e * (long)R * C;
    int x0 = blockIdx.x * 32;
    int y0 = blockIdx.y * 32;
    int tx = threadIdx.x, ty = threadIdx.y;
#pragma unroll
    for (int i = 0; i < 4; ++i)
        tile[ty + i * 8][tx] = in_e[(long)(y0 + ty + i * 8) * C + x0 + tx];
    __syncthreads();
#pragma unroll
    for (int i = 0; i < 4; ++i)
        out_e[(long)(x0 + ty + i * 8) * R + y0 + tx] = f2bf(tile[tx][ty + i * 8]);
}

// ---------------- grouped GEMM: 128x128 tile, BK=32, 4 waves --------------
// PHASE 1: h = gelu(Xg @ W_in[e] + b_in[e])    (A = gathered x rows, bf16)
// PHASE 2: out += w * (h @ W_out[e] + b_out[e]) (atomicAdd scatter)
template <int PHASE>
__launch_bounds__(256, 2)
__global__ void moe_gemm_kernel(const unsigned short* __restrict__ A_src,
                                const unsigned short* __restrict__ B_src,  // [E][N][K] bf16
                                const float* __restrict__ bias,            // [E][N]
                                const int* __restrict__ offsets,
                                const int* __restrict__ perm_token,
                                const float* __restrict__ perm_weight,
                                unsigned short* __restrict__ h_buf,
                                float* __restrict__ out) {
    constexpr int Ksz = (PHASE == 1) ? D_ : H_;
    constexpr int Nsz = (PHASE == 1) ? H_ : D_;
    const int e = blockIdx.z;
    const int off_e = offsets[e];
    const int n_e = offsets[e + 1] - off_e;
    const int m0 = blockIdx.x * 128;
    if (m0 >= n_e) return;
    const int n0 = blockIdx.y * 128;

    __shared__ __attribute__((aligned(16))) unsigned short lds_a[128 * 40];
    __shared__ __attribute__((aligned(16))) unsigned short lds_b[128 * 40];

    const int tid = threadIdx.x;
    const int lane = tid & 63;
    const int wave = tid >> 6;
    const int wm = (wave >> 1) * 64;
    const int wn = (wave & 1) * 64;
    const int lrow = lane & 15;
    const int kg = lane >> 4;

    const int srow = tid >> 2;       // 0..63 (two passes cover 128 rows)
    const int sk8 = (tid & 3) * 8;   // k offset within BK=32

    const unsigned short* a_row_ptr[2];
#pragma unroll
    for (int j = 0; j < 2; ++j) {
        int r = srow + j * 64;
        int m_loc = m0 + r;
        int m_cl = (m_loc < n_e) ? m_loc : (n_e - 1);
        int pos = off_e + m_cl;
        long arow;
        if (PHASE == 1) arow = (long)perm_token[pos] * Ksz;
        else            arow = (long)pos * Ksz;
        a_row_ptr[j] = A_src + arow;
    }
    const unsigned short* b_base = B_src + (long)e * Nsz * Ksz;

    f32x4_t acc[4][4];
#pragma unroll
    for (int i = 0; i < 4; ++i)
#pragma unroll
        for (int j = 0; j < 4; ++j)
            acc[i][j] = (f32x4_t){0.f, 0.f, 0.f, 0.f};

    for (int k0 = 0; k0 < Ksz; k0 += 32) {
        __syncthreads();
#pragma unroll
        for (int j = 0; j < 2; ++j) {
            int r = srow + j * 64;
            uint4 av = *reinterpret_cast<const uint4*>(a_row_ptr[j] + k0 + sk8);
            *reinterpret_cast<uint4*>(&lds_a[r * 40 + sk8]) = av;
            uint4 bv = *reinterpret_cast<const uint4*>(b_base + (long)(n0 + r) * Ksz + k0 + sk8);
            *reinterpret_cast<uint4*>(&lds_b[r * 40 + sk8]) = bv;
        }
        __syncthreads();
        bf16x8_t a_frag[4], b_frag[4];
#pragma unroll
        for (int i = 0; i < 4; ++i) {
            a_frag[i] = *reinterpret_cast<const bf16x8_t*>(&lds_a[(wm + i * 16 + lrow) * 40 + kg * 8]);
            b_frag[i] = *reinterpret_cast<const bf16x8_t*>(&lds_b[(wn + i * 16 + lrow) * 40 + kg * 8]);
        }
#pragma unroll
        for (int i = 0; i < 4; ++i)
#pragma unroll
            for (int j = 0; j < 4; ++j)
                acc[i][j] = __builtin_amdgcn_mfma_f32_16x16x32_bf16(a_frag[i], b_frag[j], acc[i][j], 0, 0, 0);
    }

    const float* bias_e = bias + (long)e * Nsz;
#pragma unroll
    for (int i = 0; i < 4; ++i) {
#pragma unroll
        for (int r = 0; r < 4; ++r) {
            int row_loc = wm + i * 16 + kg * 4 + r;
            int m_loc = m0 + row_loc;
            if (m_loc >= n_e) continue;
            int pos = off_e + m_loc;
            if (PHASE == 1) {
#pragma unroll
                for (int j = 0; j < 4; ++j) {
                    int n = n0 + wn + j * 16 + lrow;
                    float v = acc[i][j][r] + bias_e[n];
                    v = 0.5f * v * (1.0f + erff(v * 0.70710678118654752440f));
                    h_buf[(long)pos * Nsz + n] = f2bf(v);
                }
            } else {
                int token = perm_token[pos];
                float wgt = perm_weight[pos];
#pragma unroll
                for (int j = 0; j < 4; ++j) {
                    int n = n0 + wn + j * 16 + lrow;
                    float v = (acc[i][j][r] + bias_e[n]) * wgt;
                    atomicAdd(&out[(long)token * Nsz + n], v);
                }
            }
        }
    }
}

extern "C" void kernel_launch(void* const* d_in, const int* in_sizes, int n_in,
                              void* d_out, int out_size, void* d_ws, size_t ws_size,
                              hipStream_t stream) {
    const float* x        = (const float*)d_in[0];
    const float* router_W = (const float*)d_in[1];
    const float* W_in     = (const float*)d_in[2];
    const float* b_in     = (const float*)d_in[3];
    const float* W_out    = (const float*)d_in[4];
    const float* b_out    = (const float*)d_in[5];
    float* out = (float*)d_out;

    char* ws = (char*)d_ws;
    size_t off = 0;
    auto alloc = [&](size_t bytes) -> void* {
        void* p = ws + off;
        off += (bytes + 255) & ~(size_t)255;
        return p;
    };

    char* ctrl = (char*)alloc(256);
    int* counts      = (int*)ctrl;
    int* cursors     = (int*)(ctrl + 32);
    float* probs_sum = (float*)(ctrl + 64);
    int* offsets     = (int*)(ctrl + 96);
    int* tok_e         = (int*)alloc((size_t)A_ * 4);
    float* tok_w       = (float*)alloc((size_t)A_ * 4);
    int* perm_token    = (int*)alloc((size_t)A_ * 4);
    float* perm_weight = (float*)alloc((size_t)A_ * 4);
    unsigned short* x_bf    = (unsigned short*)alloc((size_t)T_ * D_ * 2);
    unsigned short* w_in_t  = (unsigned short*)alloc((size_t)E_ * D_ * H_ * 2);
    unsigned short* w_out_t = (unsigned short*)alloc((size_t)E_ * D_ * H_ * 2);
    unsigned short* h_buf   = (unsigned short*)alloc((size_t)A_ * H_ * 2);

    hipMemsetAsync(ctrl, 0, 256, stream);
    hipMemsetAsync(d_out, 0, (size_t)out_size * sizeof(float), stream);

    cast_x_kernel<<<(T_ * D_ / 4) / 256, 256, 0, stream>>>(x, x_bf);
    transpose_cast_kernel<<<dim3(H_ / 32, D_ / 32, E_), dim3(32, 8), 0, stream>>>(W_in, w_in_t, D_, H_);
    transpose_cast_kernel<<<dim3(D_ / 32, H_ / 32, E_), dim3(32, 8), 0, stream>>>(W_out, w_out_t, H_, D_);
    router_kernel<<<T_ / 4, 256, 0, stream>>>(x, router_W, tok_e, tok_w, counts, probs_sum);
    offsets_aux_kernel<<<1, 64, 0, stream>>>(counts, probs_sum, offsets, out + (out_size - 1));
    scatter_kernel<<<A_ / 256, 256, 0, stream>>>(tok_e, tok_w, offsets, cursors, perm_token, perm_weight);

    moe_gemm_kernel<1><<<dim3(64, H_ / 128, E_), 256, 0, stream>>>(
        x_bf, w_in_t, b_in, offsets, perm_token, perm_weight, h_buf, out);
    moe_gemm_kernel<2><<<dim3(64, D_ / 128, E_), 256, 0, stream>>>(
        h_buf, w_out_t, b_out, offsets, perm_token, perm_weight, h_buf, out);
}

// Round 2
// 1508.133 us; speedup vs baseline: 1.0926x; 1.0926x over previous
//
#include <hip/hip_runtime.h>
#include <hip/hip_bf16.h>
#include <math.h>

#define B_ 4
#define S_ 1024
#define T_ (B_ * S_)      // 4096 tokens
#define D_ 1024
#define H_ 4096
#define E_ 8
#define K_ 2
#define A_ (T_ * K_)      // 8192 assignments

typedef __bf16 bf16x8_t __attribute__((ext_vector_type(8)));
typedef float f32x4_t __attribute__((ext_vector_type(4)));

__device__ inline unsigned short f2bf(float f) {
    __hip_bfloat16 h = __float2bfloat16(f);
    return *reinterpret_cast<unsigned short*>(&h);
}

// async global->LDS, 16B per lane. LDS dest = base + lane*16 (wave-uniform base).
__device__ __forceinline__ void gl2lds16(const unsigned short* g, unsigned short* l) {
    auto* gp = reinterpret_cast<const __attribute__((address_space(1))) unsigned int*>(
        reinterpret_cast<uintptr_t>(g));
    auto* lp = reinterpret_cast<__attribute__((address_space(3))) unsigned int*>(
        reinterpret_cast<uintptr_t>(l));
    __builtin_amdgcn_global_load_lds(gp, lp, 16, 0, 0);
}

// ---------------- router: logits -> softmax -> top2 -> weights + stats ----
__global__ void router_kernel(const float* __restrict__ x, const float* __restrict__ rw,
                              int* __restrict__ tok_e, float* __restrict__ tok_w,
                              int* __restrict__ counts, float* __restrict__ probs_sum) {
    int wave = threadIdx.x >> 6;
    int lane = threadIdx.x & 63;
    int token = blockIdx.x * 4 + wave;
    if (token >= T_) return;
    const float* xr = x + (long)token * D_;
    float acc[E_];
#pragma unroll
    for (int e = 0; e < E_; ++e) acc[e] = 0.f;
    for (int i = 0; i < D_ / 64; ++i) {
        int d = i * 64 + lane;
        float xv = xr[d];
        const float* w = rw + (long)d * E_;
#pragma unroll
        for (int e = 0; e < E_; ++e) acc[e] += xv * w[e];
    }
#pragma unroll
    for (int e = 0; e < E_; ++e) {
        for (int off = 32; off > 0; off >>= 1)
            acc[e] += __shfl_down(acc[e], off);
    }
    if (lane == 0) {
        float m = acc[0];
        for (int e = 1; e < E_; ++e) m = fmaxf(m, acc[e]);
        float p[E_], s = 0.f;
        for (int e = 0; e < E_; ++e) { p[e] = expf(acc[e] - m); s += p[e]; }
        float inv = 1.f / s;
        for (int e = 0; e < E_; ++e) p[e] *= inv;
        int i0 = 0;
        for (int e = 1; e < E_; ++e) if (p[e] > p[i0]) i0 = e;
        int i1 = (i0 == 0) ? 1 : 0;
        for (int e = 0; e < E_; ++e) if (e != i0 && p[e] > p[i1]) i1 = e;
        float w0 = p[i0], w1 = p[i1];
        float inv2 = 1.f / (w0 + w1 + 1e-8f);
        w0 *= inv2; w1 *= inv2;
        tok_e[token * 2] = i0;
        tok_e[token * 2 + 1] = i1;
        tok_w[token * 2] = w0;
        tok_w[token * 2 + 1] = w1;
        atomicAdd(&counts[i0], 1);
        atomicAdd(&counts[i1], 1);
        for (int e = 0; e < E_; ++e) atomicAdd(&probs_sum[e], p[e]);
    }
}

// ---------------- offsets (serial, E=8) + aux loss ------------------------
__global__ void offsets_aux_kernel(const int* __restrict__ counts,
                                   const float* __restrict__ probs_sum,
                                   int* __restrict__ offsets, float* __restrict__ aux_out) {
    if (threadIdx.x == 0 && blockIdx.x == 0) {
        int run = 0;
        for (int e = 0; e < E_; ++e) { offsets[e] = run; run += counts[e]; }
        offsets[E_] = run;
        float aux = 0.f;
        for (int e = 0; e < E_; ++e)
            aux += (probs_sum[e] / (float)T_) * ((float)counts[e] / (float)A_);
        *aux_out = (float)E_ * aux;
    }
}

// ---------------- scatter assignments into per-expert groups --------------
__global__ void scatter_kernel(const int* __restrict__ tok_e, const float* __restrict__ tok_w,
                               const int* __restrict__ offsets, int* __restrict__ cursors,
                               int* __restrict__ perm_token, float* __restrict__ perm_weight,
                               int* __restrict__ inv_pos) {
    int i = blockIdx.x * blockDim.x + threadIdx.x;
    if (i >= A_) return;
    int e = tok_e[i];
    float w = tok_w[i];
    int pos = offsets[e] + atomicAdd(&cursors[e], 1);
    perm_token[pos] = i >> 1;
    perm_weight[pos] = w;
    inv_pos[i] = pos;
}

// ---------------- fp32 -> bf16 cast of x ----------------------------------
__global__ void cast_x_kernel(const float* __restrict__ x, unsigned short* __restrict__ xb) {
    long i = (long)blockIdx.x * blockDim.x + threadIdx.x;
    float4 v = reinterpret_cast<const float4*>(x)[i];
    unsigned long long packed = (unsigned long long)f2bf(v.x)
        | ((unsigned long long)f2bf(v.y) << 16)
        | ((unsigned long long)f2bf(v.z) << 32)
        | ((unsigned long long)f2bf(v.w) << 48);
    reinterpret_cast<unsigned long long*>(xb)[i] = packed;
}

// ---------------- fp32 [R][C] -> bf16 [C][R] per expert -------------------
__global__ void transpose_cast_kernel(const float* __restrict__ in, unsigned short* __restrict__ out,
                                      int R, int C) {
    __shared__ float tile[32][33];
    long e = blockIdx.z;
    const float* in_e = in + e * (long)R * C;
    unsigned short* out_e = out + e * (long)R * C;
    int x0 = blockIdx.x * 32;
    int y0 = blockIdx.y * 32;
    int tx = threadIdx.x, ty = threadIdx.y;
#pragma unroll
    for (int i = 0; i < 4; ++i)
        tile[ty + i * 8][tx] = in_e[(long)(y0 + ty + i * 8) * C + x0 + tx];
    __syncthreads();
#pragma unroll
    for (int i = 0; i < 4; ++i)
        out_e[(long)(x0 + ty + i * 8) * R + y0 + tx] = f2bf(tile[tx][ty + i * 8]);
}

// ---------------- grouped GEMM: 128x128 tile, BK=32, 4 waves --------------
// LDS tiles are UNPADDED 128x32 bf16 (64B rows) as required by global_load_lds
// lane-order writes; bank spread via 16B-chunk XOR swizzle with (row>>1)&3:
//   LDS[r][c] = G[r][c ^ ((r>>1)&3)]  (c = 16B chunk index, 0..3)
// -> frag reads hit 8 distinct bank-quads per 16 lanes (2-way alias = free).
// PHASE 1: h = gelu(Xg @ W_in[e]^T + b_in[e])      -> h_buf (bf16, permuted rows)
// PHASE 2: y = (h @ W_out[e]^T + b_out[e]) * wgt   -> y_perm (fp32, permuted rows)
template <int PHASE>
__launch_bounds__(256, 3)
__global__ void moe_gemm_kernel(const unsigned short* __restrict__ A_src,
                                const unsigned short* __restrict__ B_src,  // [E][N][K] bf16
                                const float* __restrict__ bias,            // [E][N]
                                const int* __restrict__ offsets,
                                const int* __restrict__ perm_token,
                                const float* __restrict__ perm_weight,
                                unsigned short* __restrict__ h_buf,
                                float* __restrict__ y_perm) {
    constexpr int Ksz = (PHASE == 1) ? D_ : H_;
    constexpr int Nsz = (PHASE == 1) ? H_ : D_;
    const int e = blockIdx.z;
    const int off_e = offsets[e];
    const int n_e = offsets[e + 1] - off_e;
    const int m0 = blockIdx.x * 128;
    if (m0 >= n_e) return;
    const int n0 = blockIdx.y * 128;

    __shared__ __attribute__((aligned(16))) unsigned short lds_a[128 * 32];
    __shared__ __attribute__((aligned(16))) unsigned short lds_b[128 * 32];

    const int tid = threadIdx.x;
    const int lane = tid & 63;
    const int wave = tid >> 6;
    const int wm = (wave >> 1) * 64;
    const int wn = (wave & 1) * 64;
    const int lrow = lane & 15;
    const int kg = lane >> 4;

    // ---- staging geometry: instr j in {0,1}; group g = j*4+wave covers rows
    // g*16..g*16+15; lane covers row g*16+(lane>>2), chunk (lane&3).
    const unsigned short* gA[2];
    const unsigned short* gB[2];
    unsigned short* ldsA[2];
    unsigned short* ldsB[2];
#pragma unroll
    for (int j = 0; j < 2; ++j) {
        const int g = j * 4 + wave;
        const int r = g * 16 + (lane >> 2);
        const int c = lane & 3;
        const int sc = c ^ ((r >> 1) & 3);          // swizzled source chunk
        int m_loc = m0 + r;
        int m_cl = (m_loc < n_e) ? m_loc : (n_e - 1);
        int pos = off_e + m_cl;
        long arow;
        if (PHASE == 1) arow = (long)perm_token[pos] * Ksz;
        else            arow = (long)pos * Ksz;
        gA[j] = A_src + arow + sc * 8;
        gB[j] = B_src + (long)e * Nsz * Ksz + (long)(n0 + r) * Ksz + sc * 8;
        ldsA[j] = lds_a + g * 512;                  // lane writes base + lane*16B
        ldsB[j] = lds_b + g * 512;
    }

    // ---- loop-invariant swizzled frag offsets (shorts) ----
    int a_off[4], b_off[4];
#pragma unroll
    for (int i = 0; i < 4; ++i) {
        const int rr = wm + i * 16 + lrow;
        a_off[i] = rr * 32 + ((kg ^ ((rr >> 1) & 3)) * 8);
        const int cc = wn + i * 16 + lrow;
        b_off[i] = cc * 32 + ((kg ^ ((cc >> 1) & 3)) * 8);
    }

    f32x4_t acc[4][4];
#pragma unroll
    for (int i = 0; i < 4; ++i)
#pragma unroll
        for (int j = 0; j < 4; ++j)
            acc[i][j] = (f32x4_t){0.f, 0.f, 0.f, 0.f};

    for (int k0 = 0; k0 < Ksz; k0 += 32) {
        __syncthreads();                 // prev frag reads done before overwrite
        gl2lds16(gA[0], ldsA[0]);
        gl2lds16(gA[1], ldsA[1]);
        gl2lds16(gB[0], ldsB[0]);
        gl2lds16(gB[1], ldsB[1]);
        gA[0] += 32; gA[1] += 32; gB[0] += 32; gB[1] += 32;
        __syncthreads();                 // vmcnt(0) drain: tiles landed

        bf16x8_t a_frag[4], b_frag[4];
#pragma unroll
        for (int i = 0; i < 4; ++i) {
            a_frag[i] = *reinterpret_cast<const bf16x8_t*>(&lds_a[a_off[i]]);
            b_frag[i] = *reinterpret_cast<const bf16x8_t*>(&lds_b[b_off[i]]);
        }
#pragma unroll
        for (int i = 0; i < 4; ++i)
#pragma unroll
            for (int j = 0; j < 4; ++j)
                acc[i][j] = __builtin_amdgcn_mfma_f32_16x16x32_bf16(a_frag[i], b_frag[j], acc[i][j], 0, 0, 0);
    }

    const float* bias_e = bias + (long)e * Nsz;
#pragma unroll
    for (int i = 0; i < 4; ++i) {
#pragma unroll
        for (int r = 0; r < 4; ++r) {
            int row_loc = wm + i * 16 + kg * 4 + r;
            int m_loc = m0 + row_loc;
            if (m_loc >= n_e) continue;
            int pos = off_e + m_loc;
            if (PHASE == 1) {
#pragma unroll
                for (int j = 0; j < 4; ++j) {
                    int n = n0 + wn + j * 16 + lrow;
                    float v = acc[i][j][r] + bias_e[n];
                    v = 0.5f * v * (1.0f + erff(v * 0.70710678118654752440f));
                    h_buf[(long)pos * Nsz + n] = f2bf(v);
                }
            } else {
                float wgt = perm_weight[pos];
#pragma unroll
                for (int j = 0; j < 4; ++j) {
                    int n = n0 + wn + j * 16 + lrow;
                    y_perm[(long)pos * Nsz + n] = (acc[i][j][r] + bias_e[n]) * wgt;
                }
            }
        }
    }
}

// ---------------- combine: out[t] = y[pos(t,0)] + y[pos(t,1)] -------------
__global__ void combine_kernel(const float* __restrict__ y_perm, const int* __restrict__ inv_pos,
                               float* __restrict__ out) {
    int t = blockIdx.x;
    int d4 = threadIdx.x;                 // 0..255, float4 index (D_/4 = 256)
    int p0 = inv_pos[t * 2];
    int p1 = inv_pos[t * 2 + 1];
    float4 a = reinterpret_cast<const float4*>(y_perm + (long)p0 * D_)[d4];
    float4 b = reinterpret_cast<const float4*>(y_perm + (long)p1 * D_)[d4];
    float4 o = {a.x + b.x, a.y + b.y, a.z + b.z, a.w + b.w};
    reinterpret_cast<float4*>(out + (long)t * D_)[d4] = o;
}

extern "C" void kernel_launch(void* const* d_in, const int* in_sizes, int n_in,
                              void* d_out, int out_size, void* d_ws, size_t ws_size,
                              hipStream_t stream) {
    const float* x        = (const float*)d_in[0];
    const float* router_W = (const float*)d_in[1];
    const float* W_in     = (const float*)d_in[2];
    const float* b_in     = (const float*)d_in[3];
    const float* W_out    = (const float*)d_in[4];
    const float* b_out    = (const float*)d_in[5];
    float* out = (float*)d_out;

    char* ws = (char*)d_ws;
    size_t off = 0;
    auto alloc = [&](size_t bytes) -> void* {
        void* p = ws + off;
        off += (bytes + 255) & ~(size_t)255;
        return p;
    };

    char* ctrl = (char*)alloc(256);
    int* counts      = (int*)ctrl;
    int* cursors     = (int*)(ctrl + 32);
    float* probs_sum = (float*)(ctrl + 64);
    int* offsets     = (int*)(ctrl + 96);
    int* tok_e         = (int*)alloc((size_t)A_ * 4);
    float* tok_w       = (float*)alloc((size_t)A_ * 4);
    int* perm_token    = (int*)alloc((size_t)A_ * 4);
    float* perm_weight = (float*)alloc((size_t)A_ * 4);
    int* inv_pos       = (int*)alloc((size_t)A_ * 4);
    unsigned short* x_bf    = (unsigned short*)alloc((size_t)T_ * D_ * 2);
    unsigned short* w_in_t  = (unsigned short*)alloc((size_t)E_ * D_ * H_ * 2);
    unsigned short* w_out_t = (unsigned short*)alloc((size_t)E_ * D_ * H_ * 2);
    unsigned short* h_buf   = (unsigned short*)alloc((size_t)A_ * H_ * 2);
    float* y_perm           = (float*)alloc((size_t)A_ * D_ * 4);

    hipMemsetAsync(ctrl, 0, 256, stream);

    cast_x_kernel<<<(T_ * D_ / 4) / 256, 256, 0, stream>>>(x, x_bf);
    transpose_cast_kernel<<<dim3(H_ / 32, D_ / 32, E_), dim3(32, 8), 0, stream>>>(W_in, w_in_t, D_, H_);
    transpose_cast_kernel<<<dim3(D_ / 32, H_ / 32, E_), dim3(32, 8), 0, stream>>>(W_out, w_out_t, H_, D_);
    router_kernel<<<T_ / 4, 256, 0, stream>>>(x, router_W, tok_e, tok_w, counts, probs_sum);
    offsets_aux_kernel<<<1, 64, 0, stream>>>(counts, probs_sum, offsets, out + (out_size - 1));
    scatter_kernel<<<A_ / 256, 256, 0, stream>>>(tok_e, tok_w, offsets, cursors,
                                                 perm_token, perm_weight, inv_pos);

    moe_gemm_kernel<1><<<dim3(64, H_ / 128, E_), 256, 0, stream>>>(
        x_bf, w_in_t, b_in, offsets, perm_token, perm_weight, h_buf, y_perm);
    moe_gemm_kernel<2><<<dim3(64, D_ / 128, E_), 256, 0, stream>>>(
        h_buf, w_out_t, b_out, offsets, perm_token, perm_weight, h_buf, y_perm);
    combine_kernel<<<T_, 256, 0, stream>>>(y_perm, inv_pos, out);
}

// Round 3
// 1112.904 us; speedup vs baseline: 1.4806x; 1.3551x over previous
//
#include <hip/hip_runtime.h>
#include <hip/hip_bf16.h>
#include <math.h>

#define B_ 4
#define S_ 1024
#define T_ (B_ * S_)      // 4096 tokens
#define D_ 1024
#define H_ 4096
#define E_ 8
#define K_ 2
#define A_ (T_ * K_)      // 8192 assignments

typedef __bf16 bf16x8_t __attribute__((ext_vector_type(8)));
typedef float f32x4_t __attribute__((ext_vector_type(4)));

__device__ inline unsigned short f2bf(float f) {
    __hip_bfloat16 h = __float2bfloat16(f);
    return *reinterpret_cast<unsigned short*>(&h);
}

// async global->LDS, 16B per lane. LDS dest = base + lane*16 (wave-uniform base).
__device__ __forceinline__ void gl2lds16(const unsigned short* g, unsigned short* l) {
    auto* gp = reinterpret_cast<const __attribute__((address_space(1))) unsigned int*>(
        reinterpret_cast<uintptr_t>(g));
    auto* lp = reinterpret_cast<__attribute__((address_space(3))) unsigned int*>(
        reinterpret_cast<uintptr_t>(l));
    __builtin_amdgcn_global_load_lds(gp, lp, 16, 0, 0);
}

// Padded control block layout (all per-expert slots 128 B apart -> no shared
// cache line between any two atomic targets):
//   counts_pad : int   at ctrl + 0    + e*128
//   probs_pad  : float at ctrl + 1024 + e*128
//   cursors_pad: int   at ctrl + 2048 + e*128
//   offsets    : int[9] at ctrl + 3072

// ---------------- router: 16 tokens/block, LDS-aggregated stats -----------
__global__ void router_kernel(const float* __restrict__ x, const float* __restrict__ rw,
                              int* __restrict__ tok_e, float* __restrict__ tok_w,
                              int* __restrict__ counts_pad, float* __restrict__ probs_pad) {
    __shared__ float s_probs[E_];
    __shared__ int s_counts[E_];
    const int tid = threadIdx.x;
    if (tid < E_) { s_probs[tid] = 0.f; s_counts[tid] = 0; }
    __syncthreads();
    const int wave = tid >> 6;
    const int lane = tid & 63;

    float wprob[E_];
    int wcount[E_];
#pragma unroll
    for (int e = 0; e < E_; ++e) { wprob[e] = 0.f; wcount[e] = 0; }

    for (int tt = 0; tt < 4; ++tt) {
        const int token = blockIdx.x * 16 + wave * 4 + tt;
        const float* xr = x + (long)token * D_;
        float acc[E_];
#pragma unroll
        for (int e = 0; e < E_; ++e) acc[e] = 0.f;
        for (int i = 0; i < D_ / 64; ++i) {
            int d = i * 64 + lane;
            float xv = xr[d];
            const float* w = rw + (long)d * E_;
#pragma unroll
            for (int e = 0; e < E_; ++e) acc[e] += xv * w[e];
        }
#pragma unroll
        for (int e = 0; e < E_; ++e) {
            for (int off = 32; off > 0; off >>= 1)
                acc[e] += __shfl_down(acc[e], off);
        }
        if (lane == 0) {
            float m = acc[0];
            for (int e = 1; e < E_; ++e) m = fmaxf(m, acc[e]);
            float p[E_], s = 0.f;
            for (int e = 0; e < E_; ++e) { p[e] = expf(acc[e] - m); s += p[e]; }
            float inv = 1.f / s;
            for (int e = 0; e < E_; ++e) { p[e] *= inv; wprob[e] += p[e]; }
            int i0 = 0;
            for (int e = 1; e < E_; ++e) if (p[e] > p[i0]) i0 = e;
            int i1 = (i0 == 0) ? 1 : 0;
            for (int e = 0; e < E_; ++e) if (e != i0 && p[e] > p[i1]) i1 = e;
            float w0 = p[i0], w1 = p[i1];
            float inv2 = 1.f / (w0 + w1 + 1e-8f);
            tok_e[token * 2] = i0;
            tok_e[token * 2 + 1] = i1;
            tok_w[token * 2] = w0 * inv2;
            tok_w[token * 2 + 1] = w1 * inv2;
            wcount[i0]++; wcount[i1]++;
        }
    }
    if (lane == 0) {
#pragma unroll
        for (int e = 0; e < E_; ++e) {
            atomicAdd(&s_probs[e], wprob[e]);
            if (wcount[e]) atomicAdd(&s_counts[e], wcount[e]);
        }
    }
    __syncthreads();
    if (tid < E_) {
        atomicAdd(&probs_pad[tid * 32], s_probs[tid]);
        if (s_counts[tid]) atomicAdd(&counts_pad[tid * 32], s_counts[tid]);
    }
}

// ---------------- offsets (serial, E=8) + aux loss ------------------------
__global__ void offsets_aux_kernel(const int* __restrict__ counts_pad,
                                   const float* __restrict__ probs_pad,
                                   int* __restrict__ offsets, float* __restrict__ aux_out) {
    if (threadIdx.x == 0 && blockIdx.x == 0) {
        int run = 0;
        for (int e = 0; e < E_; ++e) { offsets[e] = run; run += counts_pad[e * 32]; }
        offsets[E_] = run;
        float aux = 0.f;
        for (int e = 0; e < E_; ++e)
            aux += (probs_pad[e * 32] / (float)T_) * ((float)counts_pad[e * 32] / (float)A_);
        *aux_out = (float)E_ * aux;
    }
}

// ---------------- scatter: wave-aggregated ranking, padded cursors --------
__global__ void scatter_kernel(const int* __restrict__ tok_e, const float* __restrict__ tok_w,
                               const int* __restrict__ offsets, int* __restrict__ cursors_pad,
                               int* __restrict__ perm_token, float* __restrict__ perm_weight,
                               int* __restrict__ inv_pos) {
    int i = blockIdx.x * blockDim.x + threadIdx.x;
    int lane = threadIdx.x & 63;
    int e = tok_e[i];
    float w = tok_w[i];
    unsigned long long bal[E_];
#pragma unroll
    for (int q = 0; q < E_; ++q) bal[q] = __ballot(e == q);
    unsigned long long below = (lane == 63) ? ~0ull >> 1 : ((1ull << ((lane & 63) + 0)) - 1ull);
    below = (1ull << lane) - 1ull;  // lane<64; 1ull<<63 ok, lane==63 -> low 63 bits
    int rank = __popcll(bal[e] & below);
    int base = 0;
    if (lane < E_) {
        int c = __popcll(bal[lane]);
        if (c) base = atomicAdd(&cursors_pad[lane * 32], c);
    }
    int mybase = __shfl(base, e);
    int pos = offsets[e] + mybase + rank;
    perm_token[pos] = i >> 1;
    perm_weight[pos] = w;
    inv_pos[i] = pos;
}

// ---------------- fp32 -> bf16 cast of x ----------------------------------
__global__ void cast_x_kernel(const float* __restrict__ x, unsigned short* __restrict__ xb) {
    long i = (long)blockIdx.x * blockDim.x + threadIdx.x;
    float4 v = reinterpret_cast<const float4*>(x)[i];
    unsigned long long packed = (unsigned long long)f2bf(v.x)
        | ((unsigned long long)f2bf(v.y) << 16)
        | ((unsigned long long)f2bf(v.z) << 32)
        | ((unsigned long long)f2bf(v.w) << 48);
    reinterpret_cast<unsigned long long*>(xb)[i] = packed;
}

// ---------------- fp32 [R][C] -> bf16 [C][R] per expert -------------------
__global__ void transpose_cast_kernel(const float* __restrict__ in, unsigned short* __restrict__ out,
                                      int R, int C) {
    __shared__ float tile[32][33];
    long e = blockIdx.z;
    const float* in_e = in + e * (long)R * C;
    unsigned short* out_e = out + e * (long)R * C;
    int x0 = blockIdx.x * 32;
    int y0 = blockIdx.y * 32;
    int tx = threadIdx.x, ty = threadIdx.y;
#pragma unroll
    for (int i = 0; i < 4; ++i)
        tile[ty + i * 8][tx] = in_e[(long)(y0 + ty + i * 8) * C + x0 + tx];
    __syncthreads();
#pragma unroll
    for (int i = 0; i < 4; ++i)
        out_e[(long)(x0 + ty + i * 8) * R + y0 + tx] = f2bf(tile[tx][ty + i * 8]);
}

// ---------------- grouped GEMM: 128x128 tile, BK=32, 4 waves --------------
// LDS tiles UNPADDED 128x32 bf16 (64B rows) per global_load_lds lane-order;
// bank spread via 16B-chunk XOR swizzle with (row>>1)&3.
// PHASE 1: h = gelu(Xg @ W_in[e]^T + b_in[e])      -> h_buf (bf16, permuted rows)
// PHASE 2: y = (h @ W_out[e]^T + b_out[e]) * wgt   -> y_perm (fp32, permuted rows)
template <int PHASE>
__launch_bounds__(256, 3)
__global__ void moe_gemm_kernel(const unsigned short* __restrict__ A_src,
                                const unsigned short* __restrict__ B_src,  // [E][N][K] bf16
                                const float* __restrict__ bias,            // [E][N]
                                const int* __restrict__ offsets,
                                const int* __restrict__ perm_token,
                                const float* __restrict__ perm_weight,
                                unsigned short* __restrict__ h_buf,
                                float* __restrict__ y_perm) {
    constexpr int Ksz = (PHASE == 1) ? D_ : H_;
    constexpr int Nsz = (PHASE == 1) ? H_ : D_;
    const int e = blockIdx.z;
    const int off_e = offsets[e];
    const int n_e = offsets[e + 1] - off_e;
    const int m0 = blockIdx.x * 128;
    if (m0 >= n_e) return;
    const int n0 = blockIdx.y * 128;

    __shared__ __attribute__((aligned(16))) unsigned short lds_a[128 * 32];
    __shared__ __attribute__((aligned(16))) unsigned short lds_b[128 * 32];

    const int tid = threadIdx.x;
    const int lane = tid & 63;
    const int wave = tid >> 6;
    const int wm = (wave >> 1) * 64;
    const int wn = (wave & 1) * 64;
    const int lrow = lane & 15;
    const int kg = lane >> 4;

    const unsigned short* gA[2];
    const unsigned short* gB[2];
    unsigned short* ldsA[2];
    unsigned short* ldsB[2];
#pragma unroll
    for (int j = 0; j < 2; ++j) {
        const int g = j * 4 + wave;
        const int r = g * 16 + (lane >> 2);
        const int c = lane & 3;
        const int sc = c ^ ((r >> 1) & 3);          // swizzled source chunk
        int m_loc = m0 + r;
        int m_cl = (m_loc < n_e) ? m_loc : (n_e - 1);
        int pos = off_e + m_cl;
        long arow;
        if (PHASE == 1) arow = (long)perm_token[pos] * Ksz;
        else            arow = (long)pos * Ksz;
        gA[j] = A_src + arow + sc * 8;
        gB[j] = B_src + (long)e * Nsz * Ksz + (long)(n0 + r) * Ksz + sc * 8;
        ldsA[j] = lds_a + g * 512;
        ldsB[j] = lds_b + g * 512;
    }

    int a_off[4], b_off[4];
#pragma unroll
    for (int i = 0; i < 4; ++i) {
        const int rr = wm + i * 16 + lrow;
        a_off[i] = rr * 32 + ((kg ^ ((rr >> 1) & 3)) * 8);
        const int cc = wn + i * 16 + lrow;
        b_off[i] = cc * 32 + ((kg ^ ((cc >> 1) & 3)) * 8);
    }

    f32x4_t acc[4][4];
#pragma unroll
    for (int i = 0; i < 4; ++i)
#pragma unroll
        for (int j = 0; j < 4; ++j)
            acc[i][j] = (f32x4_t){0.f, 0.f, 0.f, 0.f};

    for (int k0 = 0; k0 < Ksz; k0 += 32) {
        __syncthreads();
        gl2lds16(gA[0], ldsA[0]);
        gl2lds16(gA[1], ldsA[1]);
        gl2lds16(gB[0], ldsB[0]);
        gl2lds16(gB[1], ldsB[1]);
        gA[0] += 32; gA[1] += 32; gB[0] += 32; gB[1] += 32;
        __syncthreads();

        bf16x8_t a_frag[4], b_frag[4];
#pragma unroll
        for (int i = 0; i < 4; ++i) {
            a_frag[i] = *reinterpret_cast<const bf16x8_t*>(&lds_a[a_off[i]]);
            b_frag[i] = *reinterpret_cast<const bf16x8_t*>(&lds_b[b_off[i]]);
        }
#pragma unroll
        for (int i = 0; i < 4; ++i)
#pragma unroll
            for (int j = 0; j < 4; ++j)
                acc[i][j] = __builtin_amdgcn_mfma_f32_16x16x32_bf16(a_frag[i], b_frag[j], acc[i][j], 0, 0, 0);
    }

    const float* bias_e = bias + (long)e * Nsz;
#pragma unroll
    for (int i = 0; i < 4; ++i) {
#pragma unroll
        for (int r = 0; r < 4; ++r) {
            int row_loc = wm + i * 16 + kg * 4 + r;
            int m_loc = m0 + row_loc;
            if (m_loc >= n_e) continue;
            int pos = off_e + m_loc;
            if (PHASE == 1) {
#pragma unroll
                for (int j = 0; j < 4; ++j) {
                    int n = n0 + wn + j * 16 + lrow;
                    float v = acc[i][j][r] + bias_e[n];
                    v = 0.5f * v * (1.0f + erff(v * 0.70710678118654752440f));
                    h_buf[(long)pos * Nsz + n] = f2bf(v);
                }
            } else {
                float wgt = perm_weight[pos];
#pragma unroll
                for (int j = 0; j < 4; ++j) {
                    int n = n0 + wn + j * 16 + lrow;
                    y_perm[(long)pos * Nsz + n] = (acc[i][j][r] + bias_e[n]) * wgt;
                }
            }
        }
    }
}

// ---------------- combine: out[t] = y[pos(t,0)] + y[pos(t,1)] -------------
__global__ void combine_kernel(const float* __restrict__ y_perm, const int* __restrict__ inv_pos,
                               float* __restrict__ out) {
    int t = blockIdx.x;
    int d4 = threadIdx.x;                 // 0..255, float4 index (D_/4 = 256)
    int p0 = inv_pos[t * 2];
    int p1 = inv_pos[t * 2 + 1];
    float4 a = reinterpret_cast<const float4*>(y_perm + (long)p0 * D_)[d4];
    float4 b = reinterpret_cast<const float4*>(y_perm + (long)p1 * D_)[d4];
    float4 o = {a.x + b.x, a.y + b.y, a.z + b.z, a.w + b.w};
    reinterpret_cast<float4*>(out + (long)t * D_)[d4] = o;
}

extern "C" void kernel_launch(void* const* d_in, const int* in_sizes, int n_in,
                              void* d_out, int out_size, void* d_ws, size_t ws_size,
                              hipStream_t stream) {
    const float* x        = (const float*)d_in[0];
    const float* router_W = (const float*)d_in[1];
    const float* W_in     = (const float*)d_in[2];
    const float* b_in     = (const float*)d_in[3];
    const float* W_out    = (const float*)d_in[4];
    const float* b_out    = (const float*)d_in[5];
    float* out = (float*)d_out;

    char* ws = (char*)d_ws;
    size_t off = 0;
    auto alloc = [&](size_t bytes) -> void* {
        void* p = ws + off;
        off += (bytes + 255) & ~(size_t)255;
        return p;
    };

    char* ctrl = (char*)alloc(4096);
    int* counts_pad   = (int*)ctrl;                 // e*128 B apart
    float* probs_pad  = (float*)(ctrl + 1024);
    int* cursors_pad  = (int*)(ctrl + 2048);
    int* offsets      = (int*)(ctrl + 3072);
    int* tok_e         = (int*)alloc((size_t)A_ * 4);
    float* tok_w       = (float*)alloc((size_t)A_ * 4);
    int* perm_token    = (int*)alloc((size_t)A_ * 4);
    float* perm_weight = (float*)alloc((size_t)A_ * 4);
    int* inv_pos       = (int*)alloc((size_t)A_ * 4);
    unsigned short* x_bf    = (unsigned short*)alloc((size_t)T_ * D_ * 2);
    unsigned short* w_in_t  = (unsigned short*)alloc((size_t)E_ * D_ * H_ * 2);
    unsigned short* w_out_t = (unsigned short*)alloc((size_t)E_ * D_ * H_ * 2);
    unsigned short* h_buf   = (unsigned short*)alloc((size_t)A_ * H_ * 2);
    float* y_perm           = (float*)alloc((size_t)A_ * D_ * 4);

    hipMemsetAsync(ctrl, 0, 4096, stream);

    cast_x_kernel<<<(T_ * D_ / 4) / 256, 256, 0, stream>>>(x, x_bf);
    transpose_cast_kernel<<<dim3(H_ / 32, D_ / 32, E_), dim3(32, 8), 0, stream>>>(W_in, w_in_t, D_, H_);
    transpose_cast_kernel<<<dim3(D_ / 32, H_ / 32, E_), dim3(32, 8), 0, stream>>>(W_out, w_out_t, H_, D_);
    router_kernel<<<T_ / 16, 256, 0, stream>>>(x, router_W, tok_e, tok_w, counts_pad, probs_pad);
    offsets_aux_kernel<<<1, 64, 0, stream>>>(counts_pad, probs_pad, offsets, out + (out_size - 1));
    scatter_kernel<<<A_ / 256, 256, 0, stream>>>(tok_e, tok_w, offsets, cursors_pad,
                                                 perm_token, perm_weight, inv_pos);

    moe_gemm_kernel<1><<<dim3(64, H_ / 128, E_), 256, 0, stream>>>(
        x_bf, w_in_t, b_in, offsets, perm_token, perm_weight, h_buf, y_perm);
    moe_gemm_kernel<2><<<dim3(64, D_ / 128, E_), 256, 0, stream>>>(
        h_buf, w_out_t, b_out, offsets, perm_token, perm_weight, h_buf, y_perm);
    combine_kernel<<<T_, 256, 0, stream>>>(y_perm, inv_pos, out);
}

// Round 4
// 660.818 us; speedup vs baseline: 2.4936x; 1.6841x over previous
//
#include <hip/hip_runtime.h>
#include <hip/hip_bf16.h>
#include <math.h>

#define B_ 4
#define S_ 1024
#define T_ (B_ * S_)      // 4096 tokens
#define D_ 1024
#define H_ 4096
#define E_ 8
#define K_ 2
#define A_ (T_ * K_)      // 8192 assignments
#define MAXT_ 72          // max m-tiles across experts: sum ceil(n_e/128) <= 64+7

typedef __bf16 bf16x8_t __attribute__((ext_vector_type(8)));
typedef float f32x4_t __attribute__((ext_vector_type(4)));

__device__ inline unsigned short f2bf(float f) {
    __hip_bfloat16 h = __float2bfloat16(f);
    return *reinterpret_cast<unsigned short*>(&h);
}

// async global->LDS, 16B per lane. LDS dest = base + lane*16 (wave-uniform base).
__device__ __forceinline__ void gl2lds16(const unsigned short* g, unsigned short* l) {
    auto* gp = reinterpret_cast<const __attribute__((address_space(1))) unsigned int*>(
        reinterpret_cast<uintptr_t>(g));
    auto* lp = reinterpret_cast<__attribute__((address_space(3))) unsigned int*>(
        reinterpret_cast<uintptr_t>(l));
    __builtin_amdgcn_global_load_lds(gp, lp, 16, 0, 0);
}

// Padded control block (per-expert atomic slots 128 B apart):
//   counts_pad : int   ctrl + 0    + e*128
//   probs_pad  : float ctrl + 1024 + e*128
//   cursors_pad: int   ctrl + 2048 + e*128
//   offsets    : int[9]  ctrl + 3072
//   tile_e     : int[72] ctrl + 3200
//   tile_m     : int[72] ctrl + 3584
//   n_tiles    : int     ctrl + 3968

// ---------------- router: 16 tokens/block, LDS-aggregated stats -----------
__global__ void router_kernel(const float* __restrict__ x, const float* __restrict__ rw,
                              int* __restrict__ tok_e, float* __restrict__ tok_w,
                              int* __restrict__ counts_pad, float* __restrict__ probs_pad) {
    __shared__ float s_probs[E_];
    __shared__ int s_counts[E_];
    const int tid = threadIdx.x;
    if (tid < E_) { s_probs[tid] = 0.f; s_counts[tid] = 0; }
    __syncthreads();
    const int wave = tid >> 6;
    const int lane = tid & 63;

    float wprob[E_];
    int wcount[E_];
#pragma unroll
    for (int e = 0; e < E_; ++e) { wprob[e] = 0.f; wcount[e] = 0; }

    for (int tt = 0; tt < 4; ++tt) {
        const int token = blockIdx.x * 16 + wave * 4 + tt;
        const float* xr = x + (long)token * D_;
        float acc[E_];
#pragma unroll
        for (int e = 0; e < E_; ++e) acc[e] = 0.f;
        for (int i = 0; i < D_ / 64; ++i) {
            int d = i * 64 + lane;
            float xv = xr[d];
            const float* w = rw + (long)d * E_;
#pragma unroll
            for (int e = 0; e < E_; ++e) acc[e] += xv * w[e];
        }
#pragma unroll
        for (int e = 0; e < E_; ++e) {
            for (int off = 32; off > 0; off >>= 1)
                acc[e] += __shfl_down(acc[e], off);
        }
        if (lane == 0) {
            float m = acc[0];
            for (int e = 1; e < E_; ++e) m = fmaxf(m, acc[e]);
            float p[E_], s = 0.f;
            for (int e = 0; e < E_; ++e) { p[e] = expf(acc[e] - m); s += p[e]; }
            float inv = 1.f / s;
            for (int e = 0; e < E_; ++e) { p[e] *= inv; wprob[e] += p[e]; }
            int i0 = 0;
            for (int e = 1; e < E_; ++e) if (p[e] > p[i0]) i0 = e;
            int i1 = (i0 == 0) ? 1 : 0;
            for (int e = 0; e < E_; ++e) if (e != i0 && p[e] > p[i1]) i1 = e;
            float w0 = p[i0], w1 = p[i1];
            float inv2 = 1.f / (w0 + w1 + 1e-8f);
            tok_e[token * 2] = i0;
            tok_e[token * 2 + 1] = i1;
            tok_w[token * 2] = w0 * inv2;
            tok_w[token * 2 + 1] = w1 * inv2;
            wcount[i0]++; wcount[i1]++;
        }
    }
    if (lane == 0) {
#pragma unroll
        for (int e = 0; e < E_; ++e) {
            atomicAdd(&s_probs[e], wprob[e]);
            if (wcount[e]) atomicAdd(&s_counts[e], wcount[e]);
        }
    }
    __syncthreads();
    if (tid < E_) {
        atomicAdd(&probs_pad[tid * 32], s_probs[tid]);
        if (s_counts[tid]) atomicAdd(&counts_pad[tid * 32], s_counts[tid]);
    }
}

// ------------- offsets + aux loss + compact tile table --------------------
__global__ void offsets_aux_kernel(const int* __restrict__ counts_pad,
                                   const float* __restrict__ probs_pad,
                                   int* __restrict__ offsets,
                                   int* __restrict__ tile_e, int* __restrict__ tile_m,
                                   int* __restrict__ n_tiles, float* __restrict__ aux_out) {
    if (threadIdx.x == 0 && blockIdx.x == 0) {
        int run = 0, t = 0;
        for (int e = 0; e < E_; ++e) {
            int c = counts_pad[e * 32];
            offsets[e] = run;
            for (int m0 = 0; m0 < c; m0 += 128) {
                tile_e[t] = e; tile_m[t] = m0; ++t;
            }
            run += c;
        }
        offsets[E_] = run;
        *n_tiles = t;
        float aux = 0.f;
        for (int e = 0; e < E_; ++e)
            aux += (probs_pad[e * 32] / (float)T_) * ((float)counts_pad[e * 32] / (float)A_);
        *aux_out = (float)E_ * aux;
    }
}

// ---------------- scatter: wave-aggregated ranking, padded cursors --------
__global__ void scatter_kernel(const int* __restrict__ tok_e, const float* __restrict__ tok_w,
                               const int* __restrict__ offsets, int* __restrict__ cursors_pad,
                               int* __restrict__ perm_token, float* __restrict__ perm_weight,
                               int* __restrict__ inv_pos) {
    int i = blockIdx.x * blockDim.x + threadIdx.x;
    int lane = threadIdx.x & 63;
    int e = tok_e[i];
    float w = tok_w[i];
    unsigned long long bal[E_];
#pragma unroll
    for (int q = 0; q < E_; ++q) bal[q] = __ballot(e == q);
    unsigned long long below = (1ull << lane) - 1ull;
    int rank = __popcll(bal[e] & below);
    int base = 0;
    if (lane < E_) {
        int c = __popcll(bal[lane]);
        if (c) base = atomicAdd(&cursors_pad[lane * 32], c);
    }
    int mybase = __shfl(base, e);
    int pos = offsets[e] + mybase + rank;
    perm_token[pos] = i >> 1;
    perm_weight[pos] = w;
    inv_pos[i] = pos;
}

// ---------------- fp32 -> bf16 cast of x ----------------------------------
__global__ void cast_x_kernel(const float* __restrict__ x, unsigned short* __restrict__ xb) {
    long i = (long)blockIdx.x * blockDim.x + threadIdx.x;
    float4 v = reinterpret_cast<const float4*>(x)[i];
    unsigned long long packed = (unsigned long long)f2bf(v.x)
        | ((unsigned long long)f2bf(v.y) << 16)
        | ((unsigned long long)f2bf(v.z) << 32)
        | ((unsigned long long)f2bf(v.w) << 48);
    reinterpret_cast<unsigned long long*>(xb)[i] = packed;
}

// ---------------- fp32 [R][C] -> bf16 [C][R] per expert -------------------
__global__ void transpose_cast_kernel(const float* __restrict__ in, unsigned short* __restrict__ out,
                                      int R, int C) {
    __shared__ float tile[32][33];
    long e = blockIdx.z;
    const float* in_e = in + e * (long)R * C;
    unsigned short* out_e = out + e * (long)R * C;
    int x0 = blockIdx.x * 32;
    int y0 = blockIdx.y * 32;
    int tx = threadIdx.x, ty = threadIdx.y;
#pragma unroll
    for (int i = 0; i < 4; ++i)
        tile[ty + i * 8][tx] = in_e[(long)(y0 + ty + i * 8) * C + x0 + tx];
    __syncthreads();
#pragma unroll
    for (int i = 0; i < 4; ++i)
        out_e[(long)(x0 + ty + i * 8) * R + y0 + tx] = f2bf(tile[tx][ty + i * 8]);
}

// ------------- grouped GEMM: compact grid + dbuf single-barrier K-loop ----
// 1-D grid: id = xcd-slot (id&7) | r (id>>3); r -> (nt_local = r/MAXT_,
// mt = r%MAXT_). XCD c owns n-tiles [c*NTX, (c+1)*NTX) -> per-XCD B working
// set <= 2 MB (L2-resident). tile table maps mt -> (expert, m0).
// K-loop: ONE barrier per iter; after barrier, prefetch k+1 into alternate
// LDS buffer (async), then compute from current buffer. The barrier's
// vmcnt(0) drain lands a full compute window after issue.
template <int PHASE>
__launch_bounds__(256, 4)
__global__ void moe_gemm_kernel(const unsigned short* __restrict__ A_src,
                                const unsigned short* __restrict__ B_src,  // [E][N][K] bf16
                                const float* __restrict__ bias,            // [E][N]
                                const int* __restrict__ offsets,
                                const int* __restrict__ tile_e, const int* __restrict__ tile_m,
                                const int* __restrict__ p_ntiles,
                                const int* __restrict__ perm_token,
                                const float* __restrict__ perm_weight,
                                unsigned short* __restrict__ h_buf,
                                float* __restrict__ y_perm) {
    constexpr int Ksz = (PHASE == 1) ? D_ : H_;
    constexpr int Nsz = (PHASE == 1) ? H_ : D_;
    constexpr int NTX = (Nsz / 128) / 8;   // n-tiles per XCD (4 or 1)
    const int id = blockIdx.x;
    const int c = id & 7;
    const int r = id >> 3;
    const int mt = r % MAXT_;
    if (mt >= *p_ntiles) return;
    const int nt = c * NTX + r / MAXT_;
    const int e = tile_e[mt];
    const int m0 = tile_m[mt];
    const int off_e = offsets[e];
    const int n_e = offsets[e + 1] - off_e;
    const int n0 = nt * 128;

    // double-buffered LDS: [2][128][32] bf16 each for A and B (32 KB total)
    __shared__ __attribute__((aligned(16))) unsigned short lds_a[2 * 128 * 32];
    __shared__ __attribute__((aligned(16))) unsigned short lds_b[2 * 128 * 32];

    const int tid = threadIdx.x;
    const int lane = tid & 63;
    const int wave = tid >> 6;
    const int wm = (wave >> 1) * 64;
    const int wn = (wave & 1) * 64;
    const int lrow = lane & 15;
    const int kg = lane >> 4;

    // staging geometry: instr j in {0,1}; group g=j*4+wave covers rows
    // g*16..g*16+15; lane handles row g*16+(lane>>2), 16B chunk (lane&3),
    // source chunk XOR-swizzled by (row>>1)&3 (bank spread in LDS).
    const unsigned short* gA[2];
    const unsigned short* gB[2];
    unsigned short* ldsA[2];
    unsigned short* ldsB[2];
#pragma unroll
    for (int j = 0; j < 2; ++j) {
        const int g = j * 4 + wave;
        const int rr = g * 16 + (lane >> 2);
        const int ch = lane & 3;
        const int sc = ch ^ ((rr >> 1) & 3);
        int m_loc = m0 + rr;
        int m_cl = (m_loc < n_e) ? m_loc : (n_e - 1);
        int pos = off_e + m_cl;
        long arow;
        if (PHASE == 1) arow = (long)perm_token[pos] * Ksz;
        else            arow = (long)pos * Ksz;
        gA[j] = A_src + arow + sc * 8;
        gB[j] = B_src + (long)e * Nsz * Ksz + (long)(n0 + rr) * Ksz + sc * 8;
        ldsA[j] = lds_a + g * 512;
        ldsB[j] = lds_b + g * 512;
    }

    int a_off[4], b_off[4];
#pragma unroll
    for (int i = 0; i < 4; ++i) {
        const int rr = wm + i * 16 + lrow;
        a_off[i] = rr * 32 + ((kg ^ ((rr >> 1) & 3)) * 8);
        const int cc = wn + i * 16 + lrow;
        b_off[i] = cc * 32 + ((kg ^ ((cc >> 1) & 3)) * 8);
    }

    f32x4_t acc[4][4];
#pragma unroll
    for (int i = 0; i < 4; ++i)
#pragma unroll
        for (int j = 0; j < 4; ++j)
            acc[i][j] = (f32x4_t){0.f, 0.f, 0.f, 0.f};

    // prologue: stage k0=0 into buffer 0
    gl2lds16(gA[0], ldsA[0]);
    gl2lds16(gA[1], ldsA[1]);
    gl2lds16(gB[0], ldsB[0]);
    gl2lds16(gB[1], ldsB[1]);

    for (int k0 = 0; k0 < Ksz; k0 += 32) {
        const int cur = (k0 >> 5) & 1;
        __syncthreads();   // vmcnt drain: buf[cur] ready; prev reads of buf[cur^1] done
        if (k0 + 32 < Ksz) {
            const int nxt = cur ^ 1;
            gl2lds16(gA[0] + k0 + 32, ldsA[0] + nxt * 4096);
            gl2lds16(gA[1] + k0 + 32, ldsA[1] + nxt * 4096);
            gl2lds16(gB[0] + k0 + 32, ldsB[0] + nxt * 4096);
            gl2lds16(gB[1] + k0 + 32, ldsB[1] + nxt * 4096);
        }
        const unsigned short* la = lds_a + cur * 4096;
        const unsigned short* lb = lds_b + cur * 4096;
        bf16x8_t a_frag[4], b_frag[4];
#pragma unroll
        for (int i = 0; i < 4; ++i) {
            a_frag[i] = *reinterpret_cast<const bf16x8_t*>(&la[a_off[i]]);
            b_frag[i] = *reinterpret_cast<const bf16x8_t*>(&lb[b_off[i]]);
        }
#pragma unroll
        for (int i = 0; i < 4; ++i)
#pragma unroll
            for (int j = 0; j < 4; ++j)
                acc[i][j] = __builtin_amdgcn_mfma_f32_16x16x32_bf16(a_frag[i], b_frag[j], acc[i][j], 0, 0, 0);
    }

    const float* bias_e = bias + (long)e * Nsz;
#pragma unroll
    for (int i = 0; i < 4; ++i) {
#pragma unroll
        for (int rq = 0; rq < 4; ++rq) {
            int row_loc = wm + i * 16 + kg * 4 + rq;
            int m_loc = m0 + row_loc;
            if (m_loc >= n_e) continue;
            int pos = off_e + m_loc;
            if (PHASE == 1) {
#pragma unroll
                for (int j = 0; j < 4; ++j) {
                    int n = n0 + wn + j * 16 + lrow;
                    float v = acc[i][j][rq] + bias_e[n];
                    v = 0.5f * v * (1.0f + erff(v * 0.70710678118654752440f));
                    h_buf[(long)pos * Nsz + n] = f2bf(v);
                }
            } else {
                float wgt = perm_weight[pos];
#pragma unroll
                for (int j = 0; j < 4; ++j) {
                    int n = n0 + wn + j * 16 + lrow;
                    y_perm[(long)pos * Nsz + n] = (acc[i][j][rq] + bias_e[n]) * wgt;
                }
            }
        }
    }
}

// ---------------- combine: out[t] = y[pos(t,0)] + y[pos(t,1)] -------------
__global__ void combine_kernel(const float* __restrict__ y_perm, const int* __restrict__ inv_pos,
                               float* __restrict__ out) {
    int t = blockIdx.x;
    int d4 = threadIdx.x;                 // 0..255, float4 index (D_/4 = 256)
    int p0 = inv_pos[t * 2];
    int p1 = inv_pos[t * 2 + 1];
    float4 a = reinterpret_cast<const float4*>(y_perm + (long)p0 * D_)[d4];
    float4 b = reinterpret_cast<const float4*>(y_perm + (long)p1 * D_)[d4];
    float4 o = {a.x + b.x, a.y + b.y, a.z + b.z, a.w + b.w};
    reinterpret_cast<float4*>(out + (long)t * D_)[d4] = o;
}

extern "C" void kernel_launch(void* const* d_in, const int* in_sizes, int n_in,
                              void* d_out, int out_size, void* d_ws, size_t ws_size,
                              hipStream_t stream) {
    const float* x        = (const float*)d_in[0];
    const float* router_W = (const float*)d_in[1];
    const float* W_in     = (const float*)d_in[2];
    const float* b_in     = (const float*)d_in[3];
    const float* W_out    = (const float*)d_in[4];
    const float* b_out    = (const float*)d_in[5];
    float* out = (float*)d_out;

    char* ws = (char*)d_ws;
    size_t off = 0;
    auto alloc = [&](size_t bytes) -> void* {
        void* p = ws + off;
        off += (bytes + 255) & ~(size_t)255;
        return p;
    };

    char* ctrl = (char*)alloc(4096);
    int* counts_pad   = (int*)ctrl;                 // e*128 B apart
    float* probs_pad  = (float*)(ctrl + 1024);
    int* cursors_pad  = (int*)(ctrl + 2048);
    int* offsets      = (int*)(ctrl + 3072);
    int* tile_e       = (int*)(ctrl + 3200);
    int* tile_m       = (int*)(ctrl + 3584);
    int* n_tiles      = (int*)(ctrl + 3968);
    int* tok_e         = (int*)alloc((size_t)A_ * 4);
    float* tok_w       = (float*)alloc((size_t)A_ * 4);
    int* perm_token    = (int*)alloc((size_t)A_ * 4);
    float* perm_weight = (float*)alloc((size_t)A_ * 4);
    int* inv_pos       = (int*)alloc((size_t)A_ * 4);
    unsigned short* x_bf    = (unsigned short*)alloc((size_t)T_ * D_ * 2);
    unsigned short* w_in_t  = (unsigned short*)alloc((size_t)E_ * D_ * H_ * 2);
    unsigned short* w_out_t = (unsigned short*)alloc((size_t)E_ * D_ * H_ * 2);
    unsigned short* h_buf   = (unsigned short*)alloc((size_t)A_ * H_ * 2);
    float* y_perm           = (float*)alloc((size_t)A_ * D_ * 4);

    hipMemsetAsync(ctrl, 0, 4096, stream);

    cast_x_kernel<<<(T_ * D_ / 4) / 256, 256, 0, stream>>>(x, x_bf);
    transpose_cast_kernel<<<dim3(H_ / 32, D_ / 32, E_), dim3(32, 8), 0, stream>>>(W_in, w_in_t, D_, H_);
    transpose_cast_kernel<<<dim3(D_ / 32, H_ / 32, E_), dim3(32, 8), 0, stream>>>(W_out, w_out_t, H_, D_);
    router_kernel<<<T_ / 16, 256, 0, stream>>>(x, router_W, tok_e, tok_w, counts_pad, probs_pad);
    offsets_aux_kernel<<<1, 64, 0, stream>>>(counts_pad, probs_pad, offsets,
                                             tile_e, tile_m, n_tiles, out + (out_size - 1));
    scatter_kernel<<<A_ / 256, 256, 0, stream>>>(tok_e, tok_w, offsets, cursors_pad,
                                                 perm_token, perm_weight, inv_pos);

    moe_gemm_kernel<1><<<8 * MAXT_ * (H_ / 128 / 8), 256, 0, stream>>>(
        x_bf, w_in_t, b_in, offsets, tile_e, tile_m, n_tiles,
        perm_token, perm_weight, h_buf, y_perm);
    moe_gemm_kernel<2><<<8 * MAXT_ * (D_ / 128 / 8), 256, 0, stream>>>(
        h_buf, w_out_t, b_out, offsets, tile_e, tile_m, n_tiles,
        perm_token, perm_weight, h_buf, y_perm);
    combine_kernel<<<T_, 256, 0, stream>>>(y_perm, inv_pos, out);
}